// Round 7
// baseline (218.120 us; speedup 1.0000x reference)
//
#include <hip/hip_runtime.h>

// WiredRNN one step — direct LDS-accumulator formulation (no CSR, no sort,
// no global atomics). Nodes partitioned into R ranges (RN=784, 103KB LDS f32
// acc per block) x CC=8 edge chunks; grid r*8+c so chunk c pins to XCD c.
// Partials aggc[c][b][node] summed in finish (+tanh, x-clamp, y-slice).
// inputs: 0:x(B,512) 1:states(B,N) 2:weight(E) 3:bias(N) 4:response(N)
//         5:edge_src(E int32) 6:edge_dst(E int32)
// out: y(B,256) then new_states(B,N), f32, concatenated flat.

#define BATCH 32
#define N_IN 512
#define N_OUT 256
#define RN 784       // nodes per range: acc[RN][33] f32 = 103488 B LDS
#define CCH 8        // edge chunks == XCDs

static __device__ __forceinline__ unsigned short f2bf(float f) {
    unsigned u = __float_as_uint(f);
    unsigned r = (u + 0x7fffu + ((u >> 16) & 1u)) >> 16;   // RNE
    return (unsigned short)r;
}

// ---- transpose states (B,N) f32 -> sTb (N,32) bf16 ----
__global__ void transpose_in_kernel(const float* __restrict__ s,
                                    unsigned short* __restrict__ sTb, int N) {
    __shared__ float tile[32 * 33];
    int tx = threadIdx.x & 31;
    int ty = threadIdx.x >> 5;        // 0..31
    int n0 = blockIdx.x * 32;
    int n = n0 + tx;
    tile[ty * 33 + tx] = (n < N) ? s[(size_t)ty * N + n] : 0.f;  // ty = b
    __syncthreads();
    int nn = n0 + ty;
    if (nn < N) sTb[(size_t)nn * 32 + tx] = f2bf(tile[tx * 33 + ty]);
}

// ---- edge accumulate: block (r,c) owns nodes [r*RN, r*RN+RN) x chunk c ----
static __device__ __forceinline__ void addp(float* ap, unsigned u, float w) {
    atomicAdd(ap,     w * __uint_as_float(u << 16));           // batch 2k
    atomicAdd(ap + 1, w * __uint_as_float(u & 0xffff0000u));   // batch 2k+1
}

__global__ __launch_bounds__(1024)
void edge_acc_kernel(const unsigned short* __restrict__ sTb,
                     const int* __restrict__ edge_src,
                     const int* __restrict__ edge_dst,
                     const float* __restrict__ weight,
                     float* __restrict__ aggc,   // [CCH][32][N]
                     int N, int E, int chunk) {
    __shared__ float acc[RN * 33];
    int c = blockIdx.x & (CCH - 1);
    int r = blockIdx.x >> 3;
    int base = r * RN;
    for (int i = threadIdx.x; i < RN * 33; i += 1024) acc[i] = 0.f;
    __syncthreads();

    int e0 = c * chunk;
    int e1 = min(e0 + chunk, E);
    for (int e = e0 + (int)threadIdx.x * 4; e < e1; e += 1024 * 4) {
        int dd[4];
        int nv;
        if (e + 3 < e1) {
            int4 d4 = *reinterpret_cast<const int4*>(edge_dst + e);
            dd[0] = d4.x; dd[1] = d4.y; dd[2] = d4.z; dd[3] = d4.w;
            nv = 4;
        } else {
            nv = e1 - e;
            for (int j = 0; j < nv; ++j) dd[j] = edge_dst[e + j];
        }
        for (int j = 0; j < nv; ++j) {
            unsigned v = (unsigned)(dd[j] - base);
            if (v < RN && dd[j] >= N_IN) {
                float w = weight[e + j];
                const uint4* sp = reinterpret_cast<const uint4*>(
                    sTb + (size_t)edge_src[e + j] * 32);
                uint4 u0 = sp[0], u1 = sp[1], u2 = sp[2], u3 = sp[3];
                float* ap = acc + v * 33;
                addp(ap +  0, u0.x, w); addp(ap +  2, u0.y, w);
                addp(ap +  4, u0.z, w); addp(ap +  6, u0.w, w);
                addp(ap +  8, u1.x, w); addp(ap + 10, u1.y, w);
                addp(ap + 12, u1.z, w); addp(ap + 14, u1.w, w);
                addp(ap + 16, u2.x, w); addp(ap + 18, u2.y, w);
                addp(ap + 20, u2.z, w); addp(ap + 22, u2.w, w);
                addp(ap + 24, u3.x, w); addp(ap + 26, u3.y, w);
                addp(ap + 28, u3.z, w); addp(ap + 30, u3.w, w);
            }
        }
    }
    __syncthreads();

    // flush partials, coalesced; LDS read bank (i+b)%32 -> conflict-free
    for (int b = 0; b < BATCH; ++b) {
        for (int i = threadIdx.x; i < RN; i += 1024) {
            int node = base + i;
            if (node < N)
                aggc[((size_t)c * BATCH + b) * N + node] = acc[i * 33 + b];
        }
    }
}

// ---- finish: sum CCH partials + tanh; x-clamp; write ns (B,N) and y ----
__global__ void finish2_kernel(const float* __restrict__ aggc,
                               const float* __restrict__ x,
                               const float* __restrict__ bias,
                               const float* __restrict__ response,
                               float* __restrict__ y,
                               float* __restrict__ ns, int N) {
    int node = blockIdx.x * 256 + threadIdx.x;
    int b = blockIdx.y;
    if (node >= N) return;
    float v;
    if (node < N_IN) {
        v = x[b * N_IN + node];
    } else {
        float s = 0.f;
#pragma unroll
        for (int c = 0; c < CCH; ++c)
            s += aggc[((size_t)c * BATCH + b) * N + node];
        v = tanhf(bias[node] + response[node] * s);
    }
    ns[(size_t)b * N + node] = v;
    int k = node - (N - N_OUT);
    if (k >= 0) y[b * N_OUT + k] = v;
}

// ---- last-resort fallback (round-1) kernels ----
__global__ void edge_kernel_fb(const float* __restrict__ states,
                               const float* __restrict__ weight,
                               const int* __restrict__ edge_src,
                               const int* __restrict__ edge_dst,
                               float* __restrict__ agg, int E, int N) {
    int e = blockIdx.x * blockDim.x + threadIdx.x;
    if (e >= E) return;
    int s = edge_src[e];
    int d = edge_dst[e];
    float w = weight[e];
#pragma unroll
    for (int b = 0; b < BATCH; ++b)
        atomicAdd(agg + (size_t)b * N + d, w * states[(size_t)b * N + s]);
}

__global__ void finish_kernel_fb(const float* __restrict__ x,
                                 const float* __restrict__ agg,
                                 const float* __restrict__ bias,
                                 const float* __restrict__ response,
                                 float* __restrict__ y, float* __restrict__ ns,
                                 int N) {
    int n = blockIdx.x * blockDim.x + threadIdx.x;
    int b = blockIdx.y;
    if (n >= N) return;
    float v;
    if (n < N_IN) v = x[b * N_IN + n];
    else          v = tanhf(bias[n] + response[n] * agg[(size_t)b * N + n]);
    ns[(size_t)b * N + n] = v;
    int n0 = N - N_OUT;
    if (n >= n0) y[b * N_OUT + (n - n0)] = v;
}

extern "C" void kernel_launch(void* const* d_in, const int* in_sizes, int n_in,
                              void* d_out, int out_size, void* d_ws, size_t ws_size,
                              hipStream_t stream) {
    const float* x        = (const float*)d_in[0];
    const float* states   = (const float*)d_in[1];
    const float* weight   = (const float*)d_in[2];
    const float* bias     = (const float*)d_in[3];
    const float* response = (const float*)d_in[4];
    const int*   edge_src = (const int*)d_in[5];
    const int*   edge_dst = (const int*)d_in[6];

    int N = in_sizes[3];          // 50000
    int E = in_sizes[5];          // 800000

    float* y  = (float*)d_out;                   // (B, N_OUT)
    float* ns = (float*)d_out + BATCH * N_OUT;   // (B, N)

    int R     = (N + RN - 1) / RN;               // 64
    int chunk = (((E + CCH - 1) / CCH) + 3) & ~3;// 100000

    size_t sTb_bytes  = ((size_t)N * 32 * 2 + 15) & ~(size_t)15;
    size_t aggc_bytes = (size_t)CCH * BATCH * N * 4;   // 51.2 MB
    size_t needed = sTb_bytes + aggc_bytes + 64;

    if (ws_size < needed) {
        // fallback: atomic-scatter path (needs 6.4 MB)
        float* agg = (float*)d_ws;
        hipMemsetAsync(agg, 0, (size_t)BATCH * N * sizeof(float), stream);
        int egrid = (E + 255) / 256;
        edge_kernel_fb<<<egrid, 256, 0, stream>>>(states, weight, edge_src,
                                                  edge_dst, agg, E, N);
        dim3 fgrid((N + 255) / 256, BATCH);
        finish_kernel_fb<<<fgrid, 256, 0, stream>>>(x, agg, bias, response,
                                                    y, ns, N);
        return;
    }

    char* p = (char*)d_ws;
    unsigned short* sTb  = (unsigned short*)p;  p += sTb_bytes;
    float*          aggc = (float*)p;

    // 1. transpose states -> bf16 (N,32)
    int tgrid = (N + 31) / 32;
    transpose_in_kernel<<<tgrid, 1024, 0, stream>>>(states, sTb, N);

    // 2. edge accumulate into LDS, flush partials (no atomics to global,
    //    no memset needed: every aggc slot for node<N written exactly once)
    edge_acc_kernel<<<R * CCH, 1024, 0, stream>>>(sTb, edge_src, edge_dst,
                                                  weight, aggc, N, E, chunk);

    // 3. reduce partials + tanh + clamp + slice, direct (B,N) writes
    dim3 fgrid((N + 255) / 256, BATCH);
    finish2_kernel<<<fgrid, 256, 0, stream>>>(aggc, x, bias, response,
                                              y, ns, N);
}

// Round 9
// 178.754 us; speedup vs baseline: 1.2202x; 1.2202x over previous
//
#include <hip/hip_runtime.h>

// WiredRNN one step — LDS-accumulator formulation, wave-cooperative hits.
// Blocks (r,c): node range r (RN=784, 103KB LDS f32 acc) x edge chunk c
// (CCH=4). Scan chunk with UNIFORM per-wave trip count; ballot-compact
// in-range edges; per hit, lanes 0..31 cooperatively gather one 64B bf16
// state row and do one ds_add_f32 each. Partials aggc[c][b][node] summed in
// finish (+tanh, x-clamp, y-slice).
// Round-8 bug fixed: non-uniform loop trip count made boundary waves run
// __ballot with half the cooperative group inactive -> missing batch sums.
// inputs: 0:x(B,512) 1:states(B,N) 2:weight(E) 3:bias(N) 4:response(N)
//         5:edge_src(E int32) 6:edge_dst(E int32)
// out: y(B,256) then new_states(B,N), f32, concatenated flat.

#define BATCH 32
#define N_IN 512
#define N_OUT 256
#define RN 784       // nodes per range: acc[RN][33] f32 = 103488 B LDS
#define CCH 4        // edge chunks; grid = R*CCH = 256 = 1 block/CU

static __device__ __forceinline__ unsigned short f2bf(float f) {
    unsigned u = __float_as_uint(f);
    unsigned r = (u + 0x7fffu + ((u >> 16) & 1u)) >> 16;   // RNE
    return (unsigned short)r;
}

// ---- transpose states (B,N) f32 -> sTb (N,32) bf16 ----
__global__ void transpose_in_kernel(const float* __restrict__ s,
                                    unsigned short* __restrict__ sTb, int N) {
    __shared__ float tile[32 * 33];
    int tx = threadIdx.x & 31;
    int ty = threadIdx.x >> 5;        // 0..31
    int n0 = blockIdx.x * 32;
    int n = n0 + tx;
    tile[ty * 33 + tx] = (n < N) ? s[(size_t)ty * N + n] : 0.f;  // ty = b
    __syncthreads();
    int nn = n0 + ty;
    if (nn < N) sTb[(size_t)nn * 32 + tx] = f2bf(tile[tx * 33 + ty]);
}

// ---- edge accumulate, wave-cooperative, uniform trip count ----
__global__ __launch_bounds__(1024)
void edge_acc2_kernel(const unsigned short* __restrict__ sTb,
                      const int* __restrict__ edge_src,
                      const int* __restrict__ edge_dst,
                      const float* __restrict__ weight,
                      float* __restrict__ aggc,   // [CCH][32][N]
                      int N, int E, int chunk) {
    __shared__ float acc[RN * 33];
    int c = blockIdx.x & (CCH - 1);
    int r = blockIdx.x / CCH;
    int base = r * RN;
    for (int i = threadIdx.x; i < RN * 33; i += 1024) acc[i] = 0.f;
    __syncthreads();

    int lane = threadIdx.x & 63;
    int e0 = c * chunk;
    int e1 = min(e0 + chunk, E);
    int iters = (e1 - e0 + 4096 - 1) / 4096;      // uniform for all lanes
    for (int it = 0; it < iters; ++it) {
        int e = e0 + it * 4096 + (int)threadIdx.x * 4;
        int dd[4]; int nv;
        if (e + 4 <= e1) {
            int4 d4 = *reinterpret_cast<const int4*>(edge_dst + e);
            dd[0] = d4.x; dd[1] = d4.y; dd[2] = d4.z; dd[3] = d4.w;
            nv = 4;
        } else {
            nv = max(0, e1 - e);
            for (int j = 0; j < nv; ++j) dd[j] = edge_dst[e + j];
            for (int j = nv; j < 4; ++j) dd[j] = -1;
        }
#pragma unroll
        for (int j = 0; j < 4; ++j) {
            unsigned v = (unsigned)(dd[j] - base);
            bool hit = (j < nv) && (v < RN) && (dd[j] >= N_IN);
            int packed = 0, wbits = 0;
            if (hit) {
                packed = (int)((v << 16) | (unsigned)edge_src[e + j]);
                wbits  = __float_as_int(weight[e + j]);
            }
            unsigned long long m = __ballot(hit);
            while (m) {
                int l = __builtin_ctzll(m);
                m &= m - 1;
                int bp   = __builtin_amdgcn_readlane(packed, l);
                float bw = __int_as_float(__builtin_amdgcn_readlane(wbits, l));
                int bs = bp & 0xffff;
                int bv = ((unsigned)bp) >> 16;
                if (lane < 32) {
                    // paired lanes share one 4B load (2 bf16 batches)
                    unsigned u = *reinterpret_cast<const unsigned*>(
                        sTb + (size_t)bs * 32 + (lane & ~1));
                    float sv = (lane & 1) ? __uint_as_float(u & 0xffff0000u)
                                          : __uint_as_float(u << 16);
                    atomicAdd(&acc[bv * 33 + lane], bw * sv);
                }
            }
        }
    }
    __syncthreads();

    // flush partials, coalesced; LDS bank (i+b)%32 -> conflict-free
    for (int b = 0; b < BATCH; ++b) {
        for (int i = threadIdx.x; i < RN; i += 1024) {
            int node = base + i;
            if (node < N)
                aggc[((size_t)c * BATCH + b) * N + node] = acc[i * 33 + b];
        }
    }
}

// ---- finish: sum CCH partials + tanh; x-clamp; write ns (B,N) and y ----
__global__ void finish2_kernel(const float* __restrict__ aggc,
                               const float* __restrict__ x,
                               const float* __restrict__ bias,
                               const float* __restrict__ response,
                               float* __restrict__ y,
                               float* __restrict__ ns, int N) {
    int node = blockIdx.x * 256 + threadIdx.x;
    int b = blockIdx.y;
    if (node >= N) return;
    float v;
    if (node < N_IN) {
        v = x[b * N_IN + node];
    } else {
        float s = 0.f;
#pragma unroll
        for (int c = 0; c < CCH; ++c)
            s += aggc[((size_t)c * BATCH + b) * N + node];
        v = tanhf(bias[node] + response[node] * s);
    }
    ns[(size_t)b * N + node] = v;
    int k = node - (N - N_OUT);
    if (k >= 0) y[b * N_OUT + k] = v;
}

// ---- last-resort fallback (round-1) kernels ----
__global__ void edge_kernel_fb(const float* __restrict__ states,
                               const float* __restrict__ weight,
                               const int* __restrict__ edge_src,
                               const int* __restrict__ edge_dst,
                               float* __restrict__ agg, int E, int N) {
    int e = blockIdx.x * blockDim.x + threadIdx.x;
    if (e >= E) return;
    int s = edge_src[e];
    int d = edge_dst[e];
    float w = weight[e];
#pragma unroll
    for (int b = 0; b < BATCH; ++b)
        atomicAdd(agg + (size_t)b * N + d, w * states[(size_t)b * N + s]);
}

__global__ void finish_kernel_fb(const float* __restrict__ x,
                                 const float* __restrict__ agg,
                                 const float* __restrict__ bias,
                                 const float* __restrict__ response,
                                 float* __restrict__ y, float* __restrict__ ns,
                                 int N) {
    int n = blockIdx.x * blockDim.x + threadIdx.x;
    int b = blockIdx.y;
    if (n >= N) return;
    float v;
    if (n < N_IN) v = x[b * N_IN + n];
    else          v = tanhf(bias[n] + response[n] * agg[(size_t)b * N + n]);
    ns[(size_t)b * N + n] = v;
    int n0 = N - N_OUT;
    if (n >= n0) y[b * N_OUT + (n - n0)] = v;
}

extern "C" void kernel_launch(void* const* d_in, const int* in_sizes, int n_in,
                              void* d_out, int out_size, void* d_ws, size_t ws_size,
                              hipStream_t stream) {
    const float* x        = (const float*)d_in[0];
    const float* states   = (const float*)d_in[1];
    const float* weight   = (const float*)d_in[2];
    const float* bias     = (const float*)d_in[3];
    const float* response = (const float*)d_in[4];
    const int*   edge_src = (const int*)d_in[5];
    const int*   edge_dst = (const int*)d_in[6];

    int N = in_sizes[3];          // 50000
    int E = in_sizes[5];          // 800000

    float* y  = (float*)d_out;                   // (B, N_OUT)
    float* ns = (float*)d_out + BATCH * N_OUT;   // (B, N)

    int R     = (N + RN - 1) / RN;               // 64
    int chunk = (((E + CCH - 1) / CCH) + 3) & ~3;// 200000

    // src must fit 16 bits for the readlane pack
    bool packable = (N <= 65536);

    size_t sTb_bytes  = ((size_t)N * 32 * 2 + 15) & ~(size_t)15;
    size_t aggc_bytes = (size_t)CCH * BATCH * N * 4;   // 25.6 MB
    size_t needed = sTb_bytes + aggc_bytes + 64;

    if (ws_size < needed || !packable) {
        // fallback: atomic-scatter path (needs 6.4 MB)
        float* agg = (float*)d_ws;
        hipMemsetAsync(agg, 0, (size_t)BATCH * N * sizeof(float), stream);
        int egrid = (E + 255) / 256;
        edge_kernel_fb<<<egrid, 256, 0, stream>>>(states, weight, edge_src,
                                                  edge_dst, agg, E, N);
        dim3 fgrid((N + 255) / 256, BATCH);
        finish_kernel_fb<<<fgrid, 256, 0, stream>>>(x, agg, bias, response,
                                                    y, ns, N);
        return;
    }

    char* p = (char*)d_ws;
    unsigned short* sTb  = (unsigned short*)p;  p += sTb_bytes;
    float*          aggc = (float*)p;

    // 1. transpose states -> bf16 (N,32)
    int tgrid = (N + 31) / 32;
    transpose_in_kernel<<<tgrid, 1024, 0, stream>>>(states, sTb, N);

    // 2. edge accumulate into LDS (wave-cooperative), flush partials
    edge_acc2_kernel<<<R * CCH, 1024, 0, stream>>>(sTb, edge_src, edge_dst,
                                                   weight, aggc, N, E, chunk);

    // 3. reduce partials + tanh + clamp + slice, direct (B,N) writes
    dim3 fgrid((N + 255) / 256, BATCH);
    finish2_kernel<<<fgrid, 256, 0, stream>>>(aggc, x, bias, response,
                                              y, ns, N);
}

// Round 10
// 87.133 us; speedup vs baseline: 2.5033x; 2.0515x over previous
//
#include <hip/hip_runtime.h>

// WiredRNN one step. CSR-by-dst gather (round-6 pipeline) with:
//  (1) XCD-grouped block mapping (blockIdx = c*RPAD + r, RPAD%8==0) so all
//      chunk-blocks of a bin-range share one XCD -> edata/pcounts cache
//      lines are written by a single non-coherent L2 (kills the 4x HBM
//      write-amplification seen in round 6: WRITE_SIZE 25.8MB for 6.4MB).
//  (2) transpose_out fused into agg (agg4 writes ns (B,N) directly via an
//      LDS tile) -> nsT buffer and 12.8MB of traffic deleted.
// inputs: 0:x(B,512) 1:states(B,N) 2:weight(E) 3:bias(N) 4:response(N)
//         5:edge_src(E int32) 6:edge_dst(E int32)
// out: y(B,256) then new_states(B,N), f32, concatenated flat.

#define BATCH 32
#define N_IN 512
#define N_OUT 256
#define RB 2048      // bins per range (8 KB LDS)
#define CC 16        // edge chunks

static __device__ __forceinline__ unsigned short f2bf(float f) {
    unsigned u = __float_as_uint(f);
    unsigned r = (u + 0x7fffu + ((u >> 16) & 1u)) >> 16;   // RNE
    return (unsigned short)r;
}

// ---- pass1 (1024 thr): grid-fused {transpose states (B,N)->(N,32) bf16} +
//      {partitioned LDS hist -> pcounts[bin][c]}, XCD-grouped mapping ----
__global__ void pass1_kernel(const float* __restrict__ s,
                             unsigned short* __restrict__ sTb, int N, int tgrid,
                             const int* __restrict__ edge_dst,
                             int* __restrict__ pcounts,
                             int E, int R, int RPAD, int chunk) {
    __shared__ int shbuf[RB];            // 8 KB; transpose aliases first 4.2 KB
    if ((int)blockIdx.x < tgrid) {
        float* tile = (float*)shbuf;     // [32][33]
        int tx = threadIdx.x & 31;
        int ty = threadIdx.x >> 5;       // 0..31
        int n0 = blockIdx.x * 32;
        int n = n0 + tx;
        tile[ty * 33 + tx] = (n < N) ? s[(size_t)ty * N + n] : 0.f;  // ty=b
        __syncthreads();
        int nn = n0 + ty;
        if (nn < N) sTb[(size_t)nn * 32 + tx] = f2bf(tile[tx * 33 + ty]);
        return;
    }
    int k = blockIdx.x - tgrid;
    int r = k % RPAD;                    // XCD = (tgrid + r) % 8 for all c
    int c = k / RPAD;
    if (r >= R) return;
    int base = r * RB;
    for (int i = threadIdx.x; i < RB; i += 1024) shbuf[i] = 0;
    __syncthreads();
    int e0 = c * chunk;
    int e1 = min(e0 + chunk, E);
    for (int e = e0 + (int)threadIdx.x * 4; e < e1; e += 1024 * 4) {
        if (e + 3 < e1) {
            int4 d4 = *reinterpret_cast<const int4*>(edge_dst + e);
            int dd[4] = {d4.x, d4.y, d4.z, d4.w};
#pragma unroll
            for (int j = 0; j < 4; ++j) {
                unsigned v = (unsigned)(dd[j] - base);
                if (v < RB && dd[j] >= N_IN) atomicAdd(&shbuf[v], 1);
            }
        } else {
            for (int j = 0; j < 4 && e + j < e1; ++j) {
                int d = edge_dst[e + j];
                unsigned v = (unsigned)(d - base);
                if (v < RB && d >= N_IN) atomicAdd(&shbuf[v], 1);
            }
        }
    }
    __syncthreads();
    // every (bin,c) slot written exactly once across the grid -> no memset
    for (int i = threadIdx.x; i < RB; i += 1024)
        pcounts[(size_t)(base + i) * CC + c] = shbuf[i];
}

// ---- scanA: per-block (2048 elts) exclusive scan in place + block sums ----
__global__ void scanA_kernel(int* __restrict__ data, int* __restrict__ bsums,
                             int M) {
    __shared__ int lds[256];
    size_t base = (size_t)blockIdx.x * 2048 + (size_t)threadIdx.x * 8;
    int v[8];
    if (base + 8 <= (size_t)M) {
        int4 a = *reinterpret_cast<const int4*>(data + base);
        int4 b = *reinterpret_cast<const int4*>(data + base + 4);
        v[0]=a.x; v[1]=a.y; v[2]=a.z; v[3]=a.w;
        v[4]=b.x; v[5]=b.y; v[6]=b.z; v[7]=b.w;
    } else {
        for (int j = 0; j < 8; ++j)
            v[j] = (base + j < (size_t)M) ? data[base + j] : 0;
    }
    int s = 0;
#pragma unroll
    for (int j = 0; j < 8; ++j) s += v[j];
    lds[threadIdx.x] = s;
    __syncthreads();
    for (int off = 1; off < 256; off <<= 1) {
        int t = (threadIdx.x >= (unsigned)off) ? lds[threadIdx.x - off] : 0;
        __syncthreads();
        lds[threadIdx.x] += t;
        __syncthreads();
    }
    int run = lds[threadIdx.x] - s;
    if (base + 8 <= (size_t)M) {
        int o[8];
#pragma unroll
        for (int j = 0; j < 8; ++j) { o[j] = run; run += v[j]; }
        *reinterpret_cast<int4*>(data + base)     = make_int4(o[0],o[1],o[2],o[3]);
        *reinterpret_cast<int4*>(data + base + 4) = make_int4(o[4],o[5],o[6],o[7]);
    } else {
        for (int j = 0; j < 8; ++j) {
            if (base + j < (size_t)M) data[base + j] = run;
            run += v[j];
        }
    }
    if (threadIdx.x == 255) bsums[blockIdx.x] = lds[255];
}

// ---- scanB: exclusive scan of block sums (single block) ----
__global__ void scanB_kernel(int* __restrict__ bsums, int n) {
    __shared__ int lds[512];
    int v = ((int)threadIdx.x < n) ? bsums[threadIdx.x] : 0;
    lds[threadIdx.x] = v;
    __syncthreads();
    for (int off = 1; off < 512; off <<= 1) {
        int t = (threadIdx.x >= (unsigned)off) ? lds[threadIdx.x - off] : 0;
        __syncthreads();
        lds[threadIdx.x] += t;
        __syncthreads();
    }
    if ((int)threadIdx.x < n) bsums[threadIdx.x] = lds[threadIdx.x] - v;
}

// ---- fill3 (1024 thr): placement with LDS cursors; XCD-grouped mapping;
//      global offset = pcounts[idx] + bsums[idx>>11] (scanC fused) ----
__global__ void fill3_kernel(const int* __restrict__ edge_src,
                             const int* __restrict__ edge_dst,
                             const float* __restrict__ weight,
                             const int* __restrict__ offsets,
                             const int* __restrict__ bsums,
                             int2* __restrict__ edata,
                             int E, int R, int RPAD, int chunk) {
    __shared__ int cur[RB];
    int r = blockIdx.x % RPAD;           // XCD = r % 8 for all c
    int c = blockIdx.x / RPAD;
    if (r >= R) return;
    int base = r * RB;
    for (int i = threadIdx.x; i < RB; i += 1024) {
        size_t idx = (size_t)(base + i) * CC + c;
        cur[i] = offsets[idx] + bsums[idx >> 11];
    }
    __syncthreads();
    int e0 = c * chunk;
    int e1 = min(e0 + chunk, E);
    for (int e = e0 + (int)threadIdx.x * 4; e < e1; e += 1024 * 4) {
        if (e + 3 < e1) {
            int4 d4 = *reinterpret_cast<const int4*>(edge_dst + e);
            int dd[4] = {d4.x, d4.y, d4.z, d4.w};
#pragma unroll
            for (int j = 0; j < 4; ++j) {
                unsigned v = (unsigned)(dd[j] - base);
                if (v < RB && dd[j] >= N_IN) {
                    int pos = atomicAdd(&cur[v], 1);
                    edata[pos] = make_int2(edge_src[e + j],
                                           __float_as_int(weight[e + j]));
                }
            }
        } else {
            for (int j = 0; j < 4 && e + j < e1; ++j) {
                int d = edge_dst[e + j];
                unsigned v = (unsigned)(d - base);
                if (v < RB && d >= N_IN) {
                    int pos = atomicAdd(&cur[v], 1);
                    edata[pos] = make_int2(edge_src[e + j],
                                           __float_as_int(weight[e + j]));
                }
            }
        }
    }
}

// ---- agg4 (1024 thr): one wave per node, 16 nodes/block; z staged in LDS
//      tile; epilogue writes ns (B,N) coalesced + y slice (transpose fused) ----
__global__ __launch_bounds__(1024)
void agg4_kernel(const unsigned short* __restrict__ sTb,
                 const int2* __restrict__ edata,
                 const int* __restrict__ offsets,
                 const int* __restrict__ bsums,
                 const float* __restrict__ x,
                 const float* __restrict__ bias,
                 const float* __restrict__ response,
                 float* __restrict__ ns,
                 float* __restrict__ y, int N) {
    __shared__ float tile[16 * 33];
    int n0 = blockIdx.x * 16;
    int wid = threadIdx.x >> 6;       // 0..15 -> node
    int node = n0 + wid;
    int lane = threadIdx.x & 63;
    int q = lane & 15;                // batch pair: b0=2q, b1=2q+1
    int p = lane >> 4;                // edge slot 0..3
    if (node < N) {
        if (node < N_IN) {
            if (p == 0) {
                tile[wid * 33 + 2 * q]     = x[(2 * q) * N_IN + node];
                tile[wid * 33 + 2 * q + 1] = x[(2 * q + 1) * N_IN + node];
            }
        } else {
            size_t i0 = (size_t)node * CC;
            size_t i1 = i0 + CC;
            int beg = offsets[i0] + bsums[i0 >> 11];
            int end = offsets[i1] + bsums[i1 >> 11];
            float a0 = 0.f, a1 = 0.f;
            for (int e = beg + p; e < end; e += 4) {
                int2 ed = edata[e];
                unsigned u = *reinterpret_cast<const unsigned*>(
                    sTb + (size_t)ed.x * 32 + 2 * q);
                float w = __int_as_float(ed.y);
                a0 += w * __uint_as_float(u << 16);
                a1 += w * __uint_as_float(u & 0xffff0000u);
            }
            a0 += __shfl_xor(a0, 16, 64);
            a0 += __shfl_xor(a0, 32, 64);
            a1 += __shfl_xor(a1, 16, 64);
            a1 += __shfl_xor(a1, 32, 64);
            if (p == 0) {
                float bi = bias[node], rs = response[node];
                tile[wid * 33 + 2 * q]     = tanhf(bi + rs * a0);
                tile[wid * 33 + 2 * q + 1] = tanhf(bi + rs * a1);
            }
        }
    }
    __syncthreads();
    // epilogue: 512 threads write 16 nodes x 32 batches, coalesced rows
    int idx = threadIdx.x;
    if (idx < 512) {
        int nl = idx & 15;
        int b  = idx >> 4;
        int node2 = n0 + nl;
        if (node2 < N) {
            float v = tile[nl * 33 + b];
            ns[(size_t)b * N + node2] = v;
            int k = node2 - (N - N_OUT);
            if (k >= 0) y[b * N_OUT + k] = v;
        }
    }
}

// ---- last-resort fallback (round-1) kernels ----
__global__ void edge_kernel_fb(const float* __restrict__ states,
                               const float* __restrict__ weight,
                               const int* __restrict__ edge_src,
                               const int* __restrict__ edge_dst,
                               float* __restrict__ agg, int E, int N) {
    int e = blockIdx.x * blockDim.x + threadIdx.x;
    if (e >= E) return;
    int s = edge_src[e];
    int d = edge_dst[e];
    float w = weight[e];
#pragma unroll
    for (int b = 0; b < BATCH; ++b)
        atomicAdd(agg + (size_t)b * N + d, w * states[(size_t)b * N + s]);
}

__global__ void finish_kernel_fb(const float* __restrict__ x,
                                 const float* __restrict__ agg,
                                 const float* __restrict__ bias,
                                 const float* __restrict__ response,
                                 float* __restrict__ y, float* __restrict__ ns,
                                 int N) {
    int n = blockIdx.x * blockDim.x + threadIdx.x;
    int b = blockIdx.y;
    if (n >= N) return;
    float v;
    if (n < N_IN) v = x[b * N_IN + n];
    else          v = tanhf(bias[n] + response[n] * agg[(size_t)b * N + n]);
    ns[(size_t)b * N + n] = v;
    int n0 = N - N_OUT;
    if (n >= n0) y[b * N_OUT + (n - n0)] = v;
}

extern "C" void kernel_launch(void* const* d_in, const int* in_sizes, int n_in,
                              void* d_out, int out_size, void* d_ws, size_t ws_size,
                              hipStream_t stream) {
    const float* x        = (const float*)d_in[0];
    const float* states   = (const float*)d_in[1];
    const float* weight   = (const float*)d_in[2];
    const float* bias     = (const float*)d_in[3];
    const float* response = (const float*)d_in[4];
    const int*   edge_src = (const int*)d_in[5];
    const int*   edge_dst = (const int*)d_in[6];

    int N = in_sizes[3];          // 50000
    int E = in_sizes[5];          // 800000

    float* y  = (float*)d_out;                   // (B, N_OUT)
    float* ns = (float*)d_out + BATCH * N_OUT;   // (B, N)

    int tgrid = (N + 31) / 32;                   // 1563

    int R     = (N + RB - 1) / RB;               // 25
    int RPAD  = (R + 7) & ~7;                    // 32 (multiple of 8 XCDs)
    int NBINS = R * RB;                          // 51200
    int M     = NBINS * CC;                      // 819200
    int chunk = (((E + CC - 1) / CC) + 3) & ~3;  // 50000
    int nblkA = (M + 2047) / 2048;               // 400

    size_t edata_bytes   = ((size_t)E * 8 + 15) & ~(size_t)15;
    size_t sTb_bytes     = ((size_t)N * 32 * 2 + 15) & ~(size_t)15;
    size_t pcounts_bytes = ((size_t)M * 4 + 15) & ~(size_t)15;
    size_t bsum_bytes    = ((size_t)nblkA * 4 + 15) & ~(size_t)15;
    size_t needed = edata_bytes + sTb_bytes + pcounts_bytes + bsum_bytes + 64;

    if (ws_size < needed || nblkA > 512) {
        float* agg = (float*)d_ws;
        hipMemsetAsync(agg, 0, (size_t)BATCH * N * sizeof(float), stream);
        int egrid = (E + 255) / 256;
        edge_kernel_fb<<<egrid, 256, 0, stream>>>(states, weight, edge_src,
                                                  edge_dst, agg, E, N);
        dim3 fgrid((N + 255) / 256, BATCH);
        finish_kernel_fb<<<fgrid, 256, 0, stream>>>(x, agg, bias, response,
                                                    y, ns, N);
        return;
    }

    char* p = (char*)d_ws;
    int2*           edata   = (int2*)p;           p += edata_bytes;
    unsigned short* sTb     = (unsigned short*)p; p += sTb_bytes;
    int*            pcounts = (int*)p;            p += pcounts_bytes; // -> offsets
    int*            bsums   = (int*)p;            p += bsum_bytes;

    // 1. transpose(bf16) || partitioned hist (XCD-grouped, no atomics/memset)
    pass1_kernel<<<tgrid + CC * RPAD, 1024, 0, stream>>>(
        states, sTb, N, tgrid, edge_dst, pcounts, E, R, RPAD, chunk);

    // 2. two-level exclusive scan (scanC fused into consumers)
    scanA_kernel<<<nblkA, 256, 0, stream>>>(pcounts, bsums, M);
    scanB_kernel<<<1, 512, 0, stream>>>(bsums, nblkA);

    // 3. placement with LDS cursors (XCD-grouped: edata lines single-XCD)
    fill3_kernel<<<CC * RPAD, 1024, 0, stream>>>(edge_src, edge_dst, weight,
                                                 pcounts, bsums, edata,
                                                 E, R, RPAD, chunk);

    // 4. gather-aggregate + tanh + clamp + fused transpose-out
    int agrid = (N + 15) / 16;
    agg4_kernel<<<agrid, 1024, 0, stream>>>(sTb, edata, pcounts, bsums, x,
                                            bias, response, ns, y, N);
}